// Round 1
// baseline (90.508 us; speedup 1.0000x reference)
//
#include <hip/hip_runtime.h>

#define STEPS 32
#define H 256
#define W 256
#define R 8                // rows per wave band
#define NIMG 192
#define BLOCKS_PER_IMG 8   // 4 waves/block * 8 rows/wave = 32 rows/block

// Vertex mask: bits k..31 set, k = bin(f) = ceil(f*31) in [0,31] for f in [0,1).
// Cumulative-domain identity: a cell with bin k contributes +/-1 to ECC(t) for
// all t >= k, i.e. the mask ~0u<<k. Monotonicity gives
//   mask(max(a,b)) = mask(a) & mask(b)
// so edge/square masks are ANDs of vertex masks -- no bin maxes needed.
// Per pixel: V - HE = maskV ^ maskHE  (bits in [kv,khe), a 0/+1 mask "P")
//            Sq - VE = -(maskVE ^ maskSq) (bits in [kve,ksq), a 0/-1 mask "N")
// Accumulating P/N masks per bit position directly yields the ECC curve --
// histogram, LDS atomics, and the final cumsum scan all disappear.
__device__ __forceinline__ unsigned vmask(float f) {
    return ~0u << (int)ceilf(f * 31.0f);
}

// Bit-sliced carry-save add of a 0/1 mask into DEPTH planes (32 independent
// per-threshold counters, one per bit position). counts must stay < 2^DEPTH.
template<int DEPTH>
__device__ __forceinline__ void csa_add(unsigned* p, unsigned m) {
#pragma unroll
    for (int j = 0; j < DEPTH; ++j) {
        unsigned t = p[j] & m;
        p[j] ^= m;
        m = t;
    }
}

// Butterfly step: add partner lane's Wd-plane counter set (bitwise ripple-carry
// across planes; 32 independent Wd-bit adders in bit-parallel). Width grows by 1.
template<int Wd>
__device__ __forceinline__ void merge_xor(unsigned* a, int lanemask) {
    unsigned b[Wd];
#pragma unroll
    for (int j = 0; j < Wd; ++j) b[j] = (unsigned)__shfl_xor((int)a[j], lanemask, 64);
    unsigned carry = 0;
#pragma unroll
    for (int j = 0; j < Wd; ++j) {
        unsigned t  = a[j] ^ b[j];
        unsigned nc = (a[j] & b[j]) | (carry & t);
        a[j] = t ^ carry;
        carry = nc;
    }
    a[Wd] = carry;
}

// Zero LDS, zero __syncthreads. Same tiling as before: lane owns 4 cols,
// wave owns an 8-row band, 5-deep software-pipelined row loads kept intact.
__global__ __launch_bounds__(256) void ecc_kernel(const float* __restrict__ x,
                                                  float* __restrict__ out) {
    const int tid  = threadIdx.x;
    const int lane = tid & 63;
    const int wave = tid >> 6;
    const int bc   = blockIdx.x >> 3;  // image*channel 0..191
    const int bg   = blockIdx.x & 7;   // band group within image
    const int r0   = (bg * 4 + wave) * R;
    const float4* rowp = (const float4*)(x + (size_t)bc * (H * W)) + lane;

    const bool has_right = (lane < 63);     // col 255 has no right edge/square
    const bool last_band = (r0 + R == H);   // band containing row 255

    // P: 4 adds/iter * 8 iters = 32 <= 63 -> 6 planes; N likewise.
    // After 6 butterfly levels: counts <= 2048 -> 12 planes.
    unsigned P[12], N[12];
#pragma unroll
    for (int j = 0; j < 12; ++j) { P[j] = 0u; N[j] = 0u; }

    // prime the 5-slot register queue with rows r0..r0+4 (r0+4 <= 252, valid)
    float4 q[5];
#pragma unroll
    for (int t = 0; t < 5; ++t) q[t] = rowp[(size_t)(r0 + t) * (W / 4)];

    // current-row vertex masks + horizontal-edge masks from q[0]
    unsigned mv0 = vmask(q[0].x), mv1 = vmask(q[0].y),
             mv2 = vmask(q[0].z), mv3 = vmask(q[0].w);
    unsigned mvR = (unsigned)__shfl_down((int)mv0, 1);
    unsigned mh0 = mv0 & mv1, mh1 = mv1 & mv2, mh2 = mv2 & mv3, mh3 = mv3 & mvR;

#pragma unroll
    for (int t = 0; t < R; ++t) {
        const bool down = (t < R - 1) || !last_band;   // wave-uniform
        // next row (r0+t+1) sits in slot (t+1)%5
        float4 nq = q[(t + 1) % 5];
        unsigned nv0 = vmask(nq.x), nv1 = vmask(nq.y),
                 nv2 = vmask(nq.z), nv3 = vmask(nq.w);
        unsigned nvR = (unsigned)__shfl_down((int)nv0, 1);
        unsigned nh0 = nv0 & nv1, nh1 = nv1 & nv2, nh2 = nv2 & nv3, nh3 = nv3 & nvR;
        // prefetch row r0+t+5 into the just-freed slot t%5
        if (t <= 3 && (t < 3 || !last_band))
            q[t % 5] = rowp[(size_t)(r0 + t + 5) * (W / 4)];
        // P = vertex ^ h-edge   (lane63 px3: no right edge -> P = maskV)
        csa_add<6>(P, mv0 ^ mh0);
        csa_add<6>(P, mv1 ^ mh1);
        csa_add<6>(P, mv2 ^ mh2);
        csa_add<6>(P, mv3 ^ (has_right ? mh3 : 0u));
        if (down) {
            // N = v-edge ^ square; v-edge mask = mv&nv, square mask = mh&nh
            csa_add<6>(N, (mv0 & nv0) ^ (mh0 & nh0));
            csa_add<6>(N, (mv1 & nv1) ^ (mh1 & nh1));
            csa_add<6>(N, (mv2 & nv2) ^ (mh2 & nh2));
            csa_add<6>(N, (mv3 & nv3) ^ (has_right ? (mh3 & nh3) : 0u));
        }
        mv0 = nv0; mv1 = nv1; mv2 = nv2; mv3 = nv3;
        mh0 = nh0; mh1 = nh1; mh2 = nh2; mh3 = nh3;
    }

    // wave-level carry-save butterfly: every lane ends with the wave-total
    // bit-sliced counters (symmetric -- no readlane needed)
    merge_xor<6>(P, 1);   merge_xor<6>(N, 1);
    merge_xor<7>(P, 2);   merge_xor<7>(N, 2);
    merge_xor<8>(P, 4);   merge_xor<8>(N, 4);
    merge_xor<9>(P, 8);   merge_xor<9>(N, 8);
    merge_xor<10>(P, 16); merge_xor<10>(N, 16);
    merge_xor<11>(P, 32); merge_xor<11>(N, 32);

    // lane t extracts threshold t's signed count; masks are cumulative so this
    // IS the ECC value -- no scan. 4 waves * 8 bands merge via global atomics.
    if (lane < STEPS) {
        int s = 0;
#pragma unroll
        for (int j = 0; j < 12; ++j) {
            s += (int)((P[j] >> lane) & 1u) << j;
            s -= (int)((N[j] >> lane) & 1u) << j;
        }
        atomicAdd(&out[bc * STEPS + lane], (float)s);
    }
}

extern "C" void kernel_launch(void* const* d_in, const int* in_sizes, int n_in,
                              void* d_out, int out_size, void* d_ws, size_t ws_size,
                              hipStream_t stream) {
    const float* x = (const float*)d_in[0];
    float* out = (float*)d_out;
    // d_out is re-poisoned before every launch; we accumulate atomically into it.
    hipMemsetAsync(out, 0, (size_t)out_size * sizeof(float), stream);
    ecc_kernel<<<NIMG * BLOCKS_PER_IMG, 256, 0, stream>>>(x, out);
}

// Round 2
// 84.336 us; speedup vs baseline: 1.0732x; 1.0732x over previous
//
#include <hip/hip_runtime.h>

#define STEPS 32
#define H 256
#define W 256
#define R 16               // rows per wave band
#define NIMG 192
#define BLOCKS_PER_IMG 4   // 4 waves/block * 16 rows/wave = 64 rows/block

// bin(f) = ceil(f*31). Input uniform [0,1): k in [0,31], no clip needed
// (absmax exactly 0 across all prior rounds). Monotone => bin(max) = max(bin).
__device__ __forceinline__ int binf(float f) {
    return (int)ceilf(f * 31.0f);
}

// 64 shared histogram copies: hist[k*64 + col]. col = (lane + wave*16) & 63:
// per-wave rotation makes cross-wave atomic addresses disjoint (same lane in
// different waves no longer collides on the same word); rotation is a bijection
// so the epilogue's sum over all 64 columns is unchanged. Bank = col%32, 2-way
// aliasing per wave64 = free. ds_add no-return atomics.
// Row loop software-pipelined 5 deep: >=4 float4 loads in flight per wave.
// R=16 (vs 8) halves the band-boundary re-read (17/16 vs 9/8 amplification)
// and halves per-block fixed costs (hist init, epilogue, global atomics).
// Grid 768 = exactly 3 blocks/CU on 256 CUs.
__global__ __launch_bounds__(256) void ecc_kernel(const float* __restrict__ x,
                                                  float* __restrict__ out) {
    __shared__ int hist[STEPS * 64];   // 8 KB
    const int tid  = threadIdx.x;
    const int lane = tid & 63;
    const int wave = tid >> 6;
    const int bc   = blockIdx.x >> 2;  // image*channel 0..191
    const int bg   = blockIdx.x & 3;   // band group within image
    const int r0   = (bg * 4 + wave) * R;
    const int hcol = (lane + (wave << 4)) & 63;
    // lane owns cols 4*lane..4*lane+3; row r = rowp[r*64]
    const float4* rowp = (const float4*)(x + (size_t)bc * (H * W)) + lane;

#pragma unroll
    for (int w = 0; w < 8; ++w) hist[(w << 8) + tid] = 0;
    __syncthreads();

    const bool has_right = (lane < 63);     // col 255 has no right edge
    const bool last_band = (r0 + R == H);   // band containing row 255

#define ADD(k, v) atomicAdd(&hist[((k) << 6) + hcol], (v))

    // prime the 5-slot register queue with rows r0..r0+4 (r0+4 <= 244, valid)
    float4 q[5];
#pragma unroll
    for (int t = 0; t < 5; ++t) q[t] = rowp[(size_t)(r0 + t) * (W / 4)];

    // current-row bins + horizontal-edge maxes from q[0]
    int c0 = binf(q[0].x), c1 = binf(q[0].y), c2 = binf(q[0].z), c3 = binf(q[0].w);
    int cR = __shfl_down(c0, 1);
    int h0 = max(c0, c1), h1 = max(c1, c2), h2 = max(c2, c3), h3 = max(c3, cR);

#pragma unroll
    for (int t = 0; t < R; ++t) {
        const bool down = (t < R - 1) || !last_band;   // wave-uniform
        // next row (r0+t+1) sits in slot (t+1)%5; convert first so the slot's
        // producer load is the oldest outstanding vmcnt
        float4 nq = q[(t + 1) % 5];
        int n0 = binf(nq.x), n1 = binf(nq.y), n2 = binf(nq.z), n3 = binf(nq.w);
        int nR = __shfl_down(n0, 1);
        int g0 = max(n0, n1), g1 = max(n1, n2), g2 = max(n2, n3), g3 = max(n3, nR);
        // prefetch row r0+t+5 into the just-freed slot t%5 (cur was consumed);
        // last band stops one early (row 256 doesn't exist; stale slot unused)
        if (t <= R - 5 && (t < R - 5 || !last_band))
            q[t % 5] = rowp[(size_t)(r0 + t + 5) * (W / 4)];
        // vertices (+1)
        ADD(c0, 1); ADD(c1, 1); ADD(c2, 1); ADD(c3, 1);
        // horizontal edges (-1)
        ADD(h0, -1); ADD(h1, -1); ADD(h2, -1);
        if (has_right) ADD(h3, -1);
        if (down) {
            // vertical edges (-1)
            ADD(max(c0, n0), -1); ADD(max(c1, n1), -1);
            ADD(max(c2, n2), -1); ADD(max(c3, n3), -1);
            // squares (+1): max of the two horizontal-edge bins
            ADD(max(h0, g0), 1); ADD(max(h1, g1), 1); ADD(max(h2, g2), 1);
            if (has_right) ADD(max(h3, g3), 1);
        }
        c0 = n0; c1 = n1; c2 = n2; c3 = n3;
        h0 = g0; h1 = g1; h2 = g2; h3 = g3;
    }
#undef ADD
    __syncthreads();

    // 32 threads: sum own bin over 64 columns (rotated => distinct banks),
    // 5-step shfl_up inclusive scan = cumsum, global atomic merges bands.
    if (tid < STEPS) {
        int s = 0;
#pragma unroll 8
        for (int t = 0; t < 64; ++t)
            s += hist[(tid << 6) + ((t + tid) & 63)];
#pragma unroll
        for (int d = 1; d < STEPS; d <<= 1) {
            int u = __shfl_up(s, d);
            if (tid >= d) s += u;
        }
        atomicAdd(&out[bc * STEPS + tid], (float)s);
    }
}

extern "C" void kernel_launch(void* const* d_in, const int* in_sizes, int n_in,
                              void* d_out, int out_size, void* d_ws, size_t ws_size,
                              hipStream_t stream) {
    const float* x = (const float*)d_in[0];
    float* out = (float*)d_out;
    // d_out is re-poisoned before every launch; we accumulate atomically into it.
    hipMemsetAsync(out, 0, (size_t)out_size * sizeof(float), stream);
    ecc_kernel<<<NIMG * BLOCKS_PER_IMG, 256, 0, stream>>>(x, out);
}

// Round 3
// 84.335 us; speedup vs baseline: 1.0732x; 1.0000x over previous
//
#include <hip/hip_runtime.h>

#define STEPS 32
#define H 256
#define W 256
#define R 8                // rows per wave band
#define NIMG 192
#define BLOCKS_PER_IMG 8   // 4 waves/block * 8 rows/wave = 32 rows/block

// bin(f) = ceil(f*31). Input uniform [0,1): k in [0,31], no clip needed
// (absmax exactly 0 in all prior rounds). Monotone => bin(max(a,b)) = max(bins).
__device__ __forceinline__ int binf(float f) {
    return (int)ceilf(f * 31.0f);
}

// 64 shared histogram copies: hist[k*64 + col], col = (lane + 16*wave) & 63.
// The per-wave rotation makes the 4 waves' atomic address sets disjoint
// (R0 had all waves hitting the same 64 words -> same-address DS-RMW
// serialization); rotation is a bijection so the epilogue's 64-column sum is
// unchanged. Bank = col%32: 2-way aliasing per wave64 = free. ds_add
// no-return atomics. Row loop software-pipelined 5 deep: >=4 float4 loads
// in flight per wave at all times. Grid 1536 = 6 blocks/CU, 24 waves/CU.
__global__ __launch_bounds__(256) void ecc_kernel(const float* __restrict__ x,
                                                  float* __restrict__ out) {
    __shared__ int hist[STEPS * 64];   // 8 KB
    const int tid  = threadIdx.x;
    const int lane = tid & 63;
    const int wave = tid >> 6;
    const int bc   = blockIdx.x >> 3;  // image*channel 0..191
    const int bg   = blockIdx.x & 7;   // band group within image
    const int r0   = (bg * 4 + wave) * R;
    const int hcol = (lane + (wave << 4)) & 63;
    // lane owns cols 4*lane..4*lane+3; row r = rowp[r*64]
    const float4* rowp = (const float4*)(x + (size_t)bc * (H * W)) + lane;

#pragma unroll
    for (int w = 0; w < 8; ++w) hist[(w << 8) + tid] = 0;
    __syncthreads();

    const bool has_right = (lane < 63);     // col 255 has no right edge
    const bool last_band = (r0 + R == H);   // band containing row 255

#define ADD(k, v) atomicAdd(&hist[((k) << 6) + hcol], (v))

    // prime the 5-slot register queue with rows r0..r0+4 (r0+4 <= 252, valid)
    float4 q[5];
#pragma unroll
    for (int t = 0; t < 5; ++t) q[t] = rowp[(size_t)(r0 + t) * (W / 4)];

    // current-row bins + horizontal-edge maxes from q[0]
    int c0 = binf(q[0].x), c1 = binf(q[0].y), c2 = binf(q[0].z), c3 = binf(q[0].w);
    int cR = __shfl_down(c0, 1);
    int h0 = max(c0, c1), h1 = max(c1, c2), h2 = max(c2, c3), h3 = max(c3, cR);

#pragma unroll
    for (int t = 0; t < R; ++t) {
        const bool down = (t < R - 1) || !last_band;   // wave-uniform
        // next row (r0+t+1) sits in slot (t+1)%5; convert first so the slot's
        // producer load is the oldest outstanding vmcnt
        float4 nq = q[(t + 1) % 5];
        int n0 = binf(nq.x), n1 = binf(nq.y), n2 = binf(nq.z), n3 = binf(nq.w);
        int nR = __shfl_down(n0, 1);
        int g0 = max(n0, n1), g1 = max(n1, n2), g2 = max(n2, n3), g3 = max(n3, nR);
        // prefetch row r0+t+5 into the just-freed slot t%5 (cur was consumed)
        if (t <= 3 && (t < 3 || !last_band))
            q[t % 5] = rowp[(size_t)(r0 + t + 5) * (W / 4)];
        // vertices (+1)
        ADD(c0, 1); ADD(c1, 1); ADD(c2, 1); ADD(c3, 1);
        // horizontal edges (-1)
        ADD(h0, -1); ADD(h1, -1); ADD(h2, -1);
        if (has_right) ADD(h3, -1);
        if (down) {
            // vertical edges (-1)
            ADD(max(c0, n0), -1); ADD(max(c1, n1), -1);
            ADD(max(c2, n2), -1); ADD(max(c3, n3), -1);
            // squares (+1): max of the two horizontal-edge bins
            ADD(max(h0, g0), 1); ADD(max(h1, g1), 1); ADD(max(h2, g2), 1);
            if (has_right) ADD(max(h3, g3), 1);
        }
        c0 = n0; c1 = n1; c2 = n2; c3 = n3;
        h0 = g0; h1 = g1; h2 = g2; h3 = g3;
    }
#undef ADD
    __syncthreads();

    // 32 threads: sum own bin over 64 columns (rotated => distinct banks),
    // 5-step shfl_up inclusive scan = cumsum, global atomic merges bands.
    if (tid < STEPS) {
        int s = 0;
#pragma unroll 8
        for (int t = 0; t < 64; ++t)
            s += hist[(tid << 6) + ((t + tid) & 63)];
#pragma unroll
        for (int d = 1; d < STEPS; d <<= 1) {
            int u = __shfl_up(s, d);
            if (tid >= d) s += u;
        }
        atomicAdd(&out[bc * STEPS + tid], (float)s);
    }
}

extern "C" void kernel_launch(void* const* d_in, const int* in_sizes, int n_in,
                              void* d_out, int out_size, void* d_ws, size_t ws_size,
                              hipStream_t stream) {
    const float* x = (const float*)d_in[0];
    float* out = (float*)d_out;
    // d_out is re-poisoned before every launch; we accumulate atomically into it.
    hipMemsetAsync(out, 0, (size_t)out_size * sizeof(float), stream);
    ecc_kernel<<<NIMG * BLOCKS_PER_IMG, 256, 0, stream>>>(x, out);
}